// Round 7
// baseline (1284.546 us; speedup 1.0000x reference)
//
#include <hip/hip_runtime.h>
#include <cstdint>

#define N_NODES 100000
#define E_EDGES 1600000
#define D_IN 64
#define H_DIM 128
#define OUT_DIM 64
#define EPS_GEN 1e-7f
#define BN_EPS 1e-5f
#define NORM_EPS 1e-12f

// ---------------------------------------------------------------------------
// ATOMIC-REDUCE PIPELINE (round 7).
// Insight from rounds 5/6 counters: any 256B-granularity RANDOM HBM stream
// runs at ~2.7 TB/s (34% peak) on MI355X — the old pipeline had one such
// stage (aggregate's random edge_h reads) plus an 8.3x-amplified 8B scatter;
// the round-6 pipeline had random 256B writes + an extra 410MB round-trip.
// The segment reduction is COMMUTATIVE, so: stream edge_h SEQUENTIALLY at
// full BW and accumulate den/hn = sum(e^m), sum(m*e^m) straight into [N,64]
// f32 buffers with native float atomics (unsafeAtomicAdd ->
// global_atomic_add_f32; 51.2MB working set is memory-side-L3 resident,
// device-coherent). The CSR build (hist/scan/scatter) disappears entirely.
//   h = hn/den  (softmax max-shift cancels; m in [1e-7,~10], exp safe f32)
//   x = feats + (h/max(||h||,eps)) * ||feats|| * scale
// ---------------------------------------------------------------------------

// One wave per 8 edges: lanes 0..7 fetch {dst,src}, broadcast via shfl;
// 16 row loads in flight (8 sequential edge_h + 8 LLC-resident feats);
// then 16 wave-atomics (2 per edge: den += ex, hn += m*ex).
__global__ __launch_bounds__(256) void edge_atomic(
    const int* __restrict__ dst, const int* __restrict__ src,
    const float* __restrict__ feats, const float* __restrict__ edge_h,
    float* __restrict__ den, float* __restrict__ hn)
{
    int wid  = blockIdx.x * 4 + (threadIdx.x >> 6);   // global wave id
    int lane = threadIdx.x & 63;
    int e0 = wid * 8;                                  // exact: grid = E/32
    int d_l = 0, s_l = 0;
    if (lane < 8) {
        d_l = dst[e0 + lane];
        s_l = src[e0 + lane];
    }
    float ev[8], fv[8];
    int   du[8];
    #pragma unroll
    for (int u = 0; u < 8; u++) {
        du[u] = __shfl(d_l, u);
        int su = __shfl(s_l, u);
        ev[u] = __builtin_nontemporal_load(
                    &edge_h[(size_t)(e0 + u) * D_IN + lane]);
        fv[u] = feats[(size_t)su * D_IN + lane];
    }
    #pragma unroll
    for (int u = 0; u < 8; u++) {
        float m  = fmaxf(fv[u] + ev[u], 0.f) + EPS_GEN;
        float ex = __expf(m);
        size_t off = (size_t)du[u] * D_IN + lane;
        unsafeAtomicAdd(&den[off], ex);
        unsafeAtomicAdd(&hn[off], m * ex);
    }
}

// One wave per node: h = hn/den, then MessageNorm epilogue -> x.
__global__ __launch_bounds__(256) void finalize_x(
    const float* __restrict__ feats, const float* __restrict__ den,
    const float* __restrict__ hn, const float* __restrict__ scale,
    float* __restrict__ x)
{
    int node = blockIdx.x * 4 + (threadIdx.x >> 6);
    int lane = threadIdx.x & 63;
    if (node >= N_NODES) return;
    size_t off = (size_t)node * D_IN + lane;
    float dv = den[off];
    float h  = dv > 0.f ? hn[off] / dv : 0.f;
    float f  = feats[off];
    float s1 = h * h, s2 = f * f;
    #pragma unroll
    for (int o = 32; o > 0; o >>= 1) {
        s1 += __shfl_xor(s1, o, 64);
        s2 += __shfl_xor(s2, o, 64);
    }
    float xv = f + (h / fmaxf(sqrtf(s1), NORM_EPS)) * sqrtf(s2) * scale[0];
    x[off] = xv;
}

// ---------------------------------------------------------------------------
// GEMM1: y1 = x[N,64] @ W1[64,128] + b1, fused BN batch-stat partials.
// Block: 256 thr, tile 32 rows x 128 cols, 4x4 acc/thread. W1 in LDS (32KB).
// ---------------------------------------------------------------------------
__global__ __launch_bounds__(256) void gemm1_stats(
    const float* __restrict__ x, const float* __restrict__ W1,
    const float* __restrict__ b1, float* __restrict__ y1,
    float* __restrict__ stats)
{
    __shared__ float wlds[D_IN * H_DIM];   // 32 KB
    __shared__ float ssum[H_DIM], ssq[H_DIM];
    int tid = threadIdx.x;
    {
        const float4* wg = (const float4*)W1;
        float4* wl = (float4*)wlds;
        #pragma unroll
        for (int i = 0; i < 8; i++) wl[tid + i * 256] = wg[tid + i * 256];
    }
    if (tid < H_DIM) { ssum[tid] = 0.f; ssq[tid] = 0.f; }
    __syncthreads();

    int rg = tid >> 5, cg = tid & 31;
    int r0 = blockIdx.x * 32 + rg * 4;
    int c0 = cg * 4;
    float acc[4][4];
    {
        float4 bb = *(const float4*)(b1 + c0);
        #pragma unroll
        for (int i = 0; i < 4; i++) {
            acc[i][0] = bb.x; acc[i][1] = bb.y; acc[i][2] = bb.z; acc[i][3] = bb.w;
        }
    }
    #pragma unroll 2
    for (int kc = 0; kc < D_IN; kc += 4) {
        float4 xr[4];
        #pragma unroll
        for (int i = 0; i < 4; i++) {
            int r = r0 + i;
            xr[i] = (r < N_NODES) ? *(const float4*)(x + (size_t)r * D_IN + kc)
                                  : make_float4(0.f, 0.f, 0.f, 0.f);
        }
        #pragma unroll
        for (int kk = 0; kk < 4; kk++) {
            float4 w4 = *(const float4*)&wlds[(kc + kk) * H_DIM + c0];
            #pragma unroll
            for (int i = 0; i < 4; i++) {
                float xv = ((const float*)&xr[i])[kk];
                acc[i][0] = fmaf(xv, w4.x, acc[i][0]);
                acc[i][1] = fmaf(xv, w4.y, acc[i][1]);
                acc[i][2] = fmaf(xv, w4.z, acc[i][2]);
                acc[i][3] = fmaf(xv, w4.w, acc[i][3]);
            }
        }
    }
    float cs[4] = {0.f, 0.f, 0.f, 0.f}, cq[4] = {0.f, 0.f, 0.f, 0.f};
    #pragma unroll
    for (int i = 0; i < 4; i++) {
        int r = r0 + i;
        if (r < N_NODES) {
            *(float4*)(y1 + (size_t)r * H_DIM + c0) =
                make_float4(acc[i][0], acc[i][1], acc[i][2], acc[i][3]);
            #pragma unroll
            for (int j = 0; j < 4; j++) {
                cs[j] += acc[i][j];
                cq[j] += acc[i][j] * acc[i][j];
            }
        }
    }
    #pragma unroll
    for (int j = 0; j < 4; j++) {
        atomicAdd(&ssum[c0 + j], cs[j]);
        atomicAdd(&ssq[c0 + j], cq[j]);
    }
    __syncthreads();
    if (tid < H_DIM) {
        unsafeAtomicAdd(&stats[tid], ssum[tid]);
        unsafeAtomicAdd(&stats[H_DIM + tid], ssq[tid]);
    }
}

// ---------------------------------------------------------------------------
// GEMM2: out = relu(BN(y1)) @ W2 + b2. BN scale/shift from batch stats.
// Block: 256 thr, tile 64 rows x 64 cols, 4x4 acc/thread. W2 in LDS (32KB).
// ---------------------------------------------------------------------------
__global__ __launch_bounds__(256) void gemm2_bn(
    const float* __restrict__ y1, const float* __restrict__ W2,
    const float* __restrict__ b2, const float* __restrict__ stats,
    const float* __restrict__ gamma, const float* __restrict__ beta,
    float* __restrict__ out)
{
    __shared__ float wlds[H_DIM * OUT_DIM];   // 32 KB
    __shared__ float sc[H_DIM], sh[H_DIM];
    int tid = threadIdx.x;
    {
        const float4* wg = (const float4*)W2;
        float4* wl = (float4*)wlds;
        #pragma unroll
        for (int i = 0; i < 8; i++) wl[tid + i * 256] = wg[tid + i * 256];
    }
    if (tid < H_DIM) {
        float mean = stats[tid] * (1.f / N_NODES);
        float var  = stats[H_DIM + tid] * (1.f / N_NODES) - mean * mean;
        float rs   = rsqrtf(var + BN_EPS);
        float s    = gamma[tid] * rs;
        sc[tid] = s;
        sh[tid] = beta[tid] - mean * s;
    }
    __syncthreads();

    int rg = tid >> 4, cg = tid & 15;
    int r0 = blockIdx.x * 64 + rg * 4;
    int c0 = cg * 4;
    float acc[4][4];
    {
        float4 bb = *(const float4*)(b2 + c0);
        #pragma unroll
        for (int i = 0; i < 4; i++) {
            acc[i][0] = bb.x; acc[i][1] = bb.y; acc[i][2] = bb.z; acc[i][3] = bb.w;
        }
    }
    #pragma unroll 2
    for (int kc = 0; kc < H_DIM; kc += 4) {
        float4 sc4 = *(const float4*)&sc[kc];
        float4 sh4 = *(const float4*)&sh[kc];
        float4 yr[4];
        #pragma unroll
        for (int i = 0; i < 4; i++) {
            int r = r0 + i;
            if (r < N_NODES) {
                float4 v = *(const float4*)(y1 + (size_t)r * H_DIM + kc);
                v.x = fmaxf(fmaf(v.x, sc4.x, sh4.x), 0.f);
                v.y = fmaxf(fmaf(v.y, sc4.y, sh4.y), 0.f);
                v.z = fmaxf(fmaf(v.z, sc4.z, sh4.z), 0.f);
                v.w = fmaxf(fmaf(v.w, sc4.w, sh4.w), 0.f);
                yr[i] = v;
            } else {
                yr[i] = make_float4(0.f, 0.f, 0.f, 0.f);
            }
        }
        #pragma unroll
        for (int kk = 0; kk < 4; kk++) {
            float4 w4 = *(const float4*)&wlds[(kc + kk) * OUT_DIM + c0];
            #pragma unroll
            for (int i = 0; i < 4; i++) {
                float yv = ((const float*)&yr[i])[kk];
                acc[i][0] = fmaf(yv, w4.x, acc[i][0]);
                acc[i][1] = fmaf(yv, w4.y, acc[i][1]);
                acc[i][2] = fmaf(yv, w4.z, acc[i][2]);
                acc[i][3] = fmaf(yv, w4.w, acc[i][3]);
            }
        }
    }
    #pragma unroll
    for (int i = 0; i < 4; i++) {
        int r = r0 + i;
        if (r < N_NODES) {
            *(float4*)(out + (size_t)r * OUT_DIM + c0) =
                make_float4(acc[i][0], acc[i][1], acc[i][2], acc[i][3]);
        }
    }
}

// ---------------------------------------------------------------------------
// Workspace (4-byte elements), single contiguous memset for den+hn+stats:
//   den   float[N*64]   25.6 MB \
//   hn    float[N*64]   25.6 MB  > zeroed together (N*128 + 256 elems)
//   stats float[256]             /
//   x     float[N*64]
//   y1    float[N*128]
// Total ~128 MB (well under the ~488MB the round-6 run proved available).
// ---------------------------------------------------------------------------
extern "C" void kernel_launch(void* const* d_in, const int* in_sizes, int n_in,
                              void* d_out, int out_size, void* d_ws, size_t ws_size,
                              hipStream_t stream)
{
    const float* feats   = (const float*)d_in[0];
    const float* edge_h  = (const float*)d_in[1];
    const int*   src     = (const int*)d_in[2];
    const int*   dst     = (const int*)d_in[3];
    const float* W1      = (const float*)d_in[4];
    const float* b1      = (const float*)d_in[5];
    const float* gamma   = (const float*)d_in[6];
    const float* bn_beta = (const float*)d_in[7];
    const float* W2      = (const float*)d_in[8];
    const float* b2      = (const float*)d_in[9];
    const float* scale   = (const float*)d_in[10];
    float* out = (float*)d_out;

    const size_t ND = (size_t)N_NODES * D_IN;
    char* ws = (char*)d_ws;
    float* den   = (float*)ws;                            ws += ND * 4;
    float* hn    = (float*)ws;                            ws += ND * 4;
    float* stats = (float*)ws;                            ws += 256 * 4;
    float* xbuf  = (float*)ws;                            ws += ND * 4;
    float* y1    = (float*)ws;

    // zero den + hn + stats in one contiguous memset (~51.2 MB, ~8 us)
    hipMemsetAsync(den, 0, (ND * 2 + 256) * 4, stream);

    edge_atomic<<<E_EDGES / 32, 256, 0, stream>>>(dst, src, feats, edge_h, den, hn);
    finalize_x<<<(N_NODES + 3) / 4, 256, 0, stream>>>(feats, den, hn, scale, xbuf);
    gemm1_stats<<<(N_NODES + 31) / 32, 256, 0, stream>>>(xbuf, W1, b1, y1, stats);
    gemm2_bn<<<(N_NODES + 63) / 64, 256, 0, stream>>>(y1, W2, b2, stats, gamma, bn_beta, out);
}

// Round 8
// 887.601 us; speedup vs baseline: 1.4472x; 1.4472x over previous
//
#include <hip/hip_runtime.h>
#include <cstdint>

#define N_NODES 100000
#define E_EDGES 1600000
#define D_IN 64
#define H_DIM 128
#define OUT_DIM 64
#define EPS_GEN 1e-7f
#define BN_EPS 1e-5f
#define NORM_EPS 1e-12f

#define NBUCKET 391          // ceil(N/256): bucket b = nodes [b*256, b*256+256)
#define P1_CHUNK 4096        // edges per bin_p1 block

// Clang-native int vector for nontemporal builtins (HIP int4 is a class).
typedef int ivec4 __attribute__((ext_vector_type(4)));

// ---------------------------------------------------------------------------
// CSR build, step 1: per-dst degree histogram. ivec4 = 4 edges/thread.
// ---------------------------------------------------------------------------
__global__ __launch_bounds__(256) void hist_kernel(
    const int* __restrict__ dst, int* __restrict__ counts)
{
    int t = blockIdx.x * 256 + threadIdx.x;
    if (t < E_EDGES / 4) {
        ivec4 d = __builtin_nontemporal_load((const ivec4*)dst + t);
        atomicAdd(&counts[d.x], 1);
        atomicAdd(&counts[d.y], 1);
        atomicAdd(&counts[d.z], 1);
        atomicAdd(&counts[d.w], 1);
    }
}

// ---------------------------------------------------------------------------
// CSR build, step 2a: per-block inclusive scan of counts (256/block).
// ---------------------------------------------------------------------------
__global__ __launch_bounds__(256) void scan1(
    const int* __restrict__ counts, int* __restrict__ row_start,
    int* __restrict__ bsum)
{
    __shared__ int s[256];
    int t = threadIdx.x, g = blockIdx.x * 256 + t;
    int v = (g < N_NODES) ? counts[g] : 0;
    s[t] = v;
    __syncthreads();
    #pragma unroll
    for (int off = 1; off < 256; off <<= 1) {
        int u = (t >= off) ? s[t - off] : 0;
        __syncthreads();
        s[t] += u;
        __syncthreads();
    }
    if (g < N_NODES) row_start[g] = s[t];
    if (t == 255) bsum[blockIdx.x] = s[255];
}

// ---------------------------------------------------------------------------
// CSR build, step 2b: exclusive scan of the 391 block sums (single block).
// ---------------------------------------------------------------------------
__global__ __launch_bounds__(512) void scan2(int* __restrict__ bsum, int nb)
{
    __shared__ int s[512];
    int t = threadIdx.x;
    int v = (t < nb) ? bsum[t] : 0;
    s[t] = v;
    __syncthreads();
    #pragma unroll
    for (int off = 1; off < 512; off <<= 1) {
        int u = (t >= off) ? s[t - off] : 0;
        __syncthreads();
        s[t] += u;
        __syncthreads();
    }
    if (t < nb) bsum[t] = s[t] - v;   // exclusive
}

// ---------------------------------------------------------------------------
// CSR build, step 2c: global exclusive row_start; per-bucket write cursors
// bcur[b] = row_start[b*256] (bucket regions of the binned/adj arrays).
// ---------------------------------------------------------------------------
__global__ __launch_bounds__(256) void scan3b(
    const int* __restrict__ counts, const int* __restrict__ bsum,
    int* __restrict__ row_start, int* __restrict__ bcur)
{
    int g = blockIdx.x * 256 + threadIdx.x;
    if (g < N_NODES) {
        int incl = row_start[g];                   // from scan1
        int rs = incl - counts[g] + bsum[blockIdx.x];
        row_start[g] = rs;
        if ((g & 255) == 0) bcur[g >> 8] = rs;
    }
    if (g == 0) row_start[N_NODES] = E_EDGES;
}

// ---------------------------------------------------------------------------
// CSR build P1: bin edges by bucket = dst>>8 with LDS staging so global
// writes are contiguous runs (kills scatter_k's measured 8.3x line
// amplification on random 8B stores; runs avg ~10 edges = 84B).
// Entry pack: dst_local(8) | src(17) | eid(21) = 46 bits in a u64.
// ---------------------------------------------------------------------------
__global__ __launch_bounds__(256) void bin_p1(
    const int* __restrict__ dst, const int* __restrict__ src,
    int* __restrict__ bcur, unsigned long long* __restrict__ binned)
{
    __shared__ unsigned long long buf[P1_CHUNK];   // 32 KB
    __shared__ int cnt[NBUCKET];
    __shared__ int base_l[NBUCKET];
    __shared__ int pos[NBUCKET];
    __shared__ int gb[NBUCKET];
    __shared__ int s[256];
    int tid = threadIdx.x;
    long e0 = (long)blockIdx.x * P1_CHUNK;

    for (int b = tid; b < NBUCKET; b += 256) cnt[b] = 0;
    __syncthreads();
    // pass 1: count buckets in this chunk
    for (int i = tid; i < P1_CHUNK; i += 256) {
        long e = e0 + i;
        if (e < E_EDGES) atomicAdd(&cnt[dst[e] >> 8], 1);
    }
    __syncthreads();
    // exclusive scan of cnt[0..NBUCKET) (2 entries per thread, Hillis-Steele)
    int a0 = (2 * tid     < NBUCKET) ? cnt[2 * tid]     : 0;
    int a1 = (2 * tid + 1 < NBUCKET) ? cnt[2 * tid + 1] : 0;
    s[tid] = a0 + a1;
    __syncthreads();
    #pragma unroll
    for (int off = 1; off < 256; off <<= 1) {
        int u = (tid >= off) ? s[tid - off] : 0;
        __syncthreads();
        s[tid] += u;
        __syncthreads();
    }
    int pb = s[tid] - a0 - a1;          // exclusive base of this thread's pair
    if (2 * tid < NBUCKET)     { base_l[2 * tid] = pb;          pos[2 * tid] = pb; }
    if (2 * tid + 1 < NBUCKET) { base_l[2 * tid + 1] = pb + a0; pos[2 * tid + 1] = pb + a0; }
    __syncthreads();
    // pass 2: place packed entries grouped by bucket
    for (int i = tid; i < P1_CHUNK; i += 256) {
        long e = e0 + i;
        if (e < E_EDGES) {
            int d = dst[e], sr = src[e];
            int b = d >> 8;
            int p = atomicAdd(&pos[b], 1);
            buf[p] = ((unsigned long long)(d & 255) << 38)
                   | ((unsigned long long)(unsigned)sr << 21)
                   | (unsigned long long)e;
        }
    }
    __syncthreads();
    // claim global space per bucket
    for (int b = tid; b < NBUCKET; b += 256) {
        int c = cnt[b];
        gb[b] = c ? atomicAdd(&bcur[b], c) : 0;
    }
    __syncthreads();
    // flush: one wave per bucket, lane-parallel contiguous run copy
    int wv = tid >> 6, ln = tid & 63;
    for (int b = wv; b < NBUCKET; b += 4) {
        int c = cnt[b];
        if (!c) continue;
        int lb = base_l[b], g = gb[b];
        for (int i = ln; i < c; i += 64)
            binned[(size_t)g + i] = buf[lb + i];
    }
}

// ---------------------------------------------------------------------------
// CSR build P2: one block per bucket. Sequential read of the bucket's
// binned entries; LDS per-node cursors; adj writes land in a 32KB window
// (L2-coalesced, ~1x write amp). Produces dst-sorted adj {eid, src}.
// ---------------------------------------------------------------------------
__global__ __launch_bounds__(256) void sort_p2(
    const unsigned long long* __restrict__ binned,
    const int* __restrict__ row_start, int2* __restrict__ adj)
{
    __shared__ int ncur[256];
    int b = blockIdx.x, tid = threadIdx.x;
    int node_base = b << 8;
    int nn = min(256, N_NODES - node_base);
    int base = row_start[node_base];
    int count = row_start[min(node_base + 256, N_NODES)] - base;
    if (tid < nn) ncur[tid] = row_start[node_base + tid] - base;
    __syncthreads();
    for (int i = tid; i < count; i += 256) {
        unsigned long long v = __builtin_nontemporal_load(&binned[(size_t)base + i]);
        int dl  = (int)(v >> 38);
        int p   = atomicAdd(&ncur[dl], 1);
        int eid = (int)(v & 0x1FFFFFull);
        int sr  = (int)((v >> 21) & 0x1FFFFull);
        adj[(size_t)base + p] = make_int2(eid, sr);
    }
}

// ---------------------------------------------------------------------------
// Fused aggregation + MessageNorm (round-3 proven version, unchanged).
// One wave per node, lane = channel; adj loaded coalesced + shfl-broadcast;
// masked unroll x8 (16 row loads in flight, no serial tail); edge_h NT.
//   den = sum exp(m), hn = sum m*exp(m)  (max-shift cancels; m ~ [1e-7,10])
// ---------------------------------------------------------------------------
__global__ __launch_bounds__(256) void aggregate(
    const float* __restrict__ feats, const float* __restrict__ edge_h,
    const int2* __restrict__ adj, const int* __restrict__ row_start,
    const float* __restrict__ scale, float* __restrict__ x)
{
    int node = blockIdx.x * 4 + (threadIdx.x >> 6);
    int lane = threadIdx.x & 63;
    if (node >= N_NODES) return;
    int rs = row_start[node], re = row_start[node + 1];
    float den = 0.f, hn = 0.f;

    for (int base = rs; base < re; base += 64) {
        int rem = min(64, re - base);
        int2 ad = make_int2(0, 0);
        if (base + lane < re) {
            unsigned long long v = __builtin_nontemporal_load(
                (const unsigned long long*)&adj[base + lane]);
            ad.x = (int)(unsigned)v;
            ad.y = (int)(unsigned)(v >> 32);
        }
        for (int j = 0; j < rem; j += 8) {
            #pragma unroll
            for (int u = 0; u < 8; u++) {
                int jj = j + u;
                int eid = __shfl(ad.x, jj);
                int sid = __shfl(ad.y, jj);
                float fv = feats[(size_t)sid * D_IN + lane];
                float ev = __builtin_nontemporal_load(
                               &edge_h[(size_t)eid * D_IN + lane]);
                float m = fmaxf(fv + ev, 0.f) + EPS_GEN;
                float ex = __expf(m);
                bool ok = jj < rem;
                den += ok ? ex : 0.f;
                hn  += ok ? m * ex : 0.f;
            }
        }
    }

    float h = den > 0.f ? hn / den : 0.f;
    float f = feats[(size_t)node * D_IN + lane];
    float s1 = h * h, s2 = f * f;
    #pragma unroll
    for (int off = 32; off > 0; off >>= 1) {
        s1 += __shfl_xor(s1, off, 64);
        s2 += __shfl_xor(s2, off, 64);
    }
    float xv = f + (h / fmaxf(sqrtf(s1), NORM_EPS)) * sqrtf(s2) * scale[0];
    x[(size_t)node * D_IN + lane] = xv;
}

// ---------------------------------------------------------------------------
// GEMM1: y1 = x[N,64] @ W1[64,128] + b1, fused BN batch-stat partials.
// ---------------------------------------------------------------------------
__global__ __launch_bounds__(256) void gemm1_stats(
    const float* __restrict__ x, const float* __restrict__ W1,
    const float* __restrict__ b1, float* __restrict__ y1,
    float* __restrict__ stats)
{
    __shared__ float wlds[D_IN * H_DIM];   // 32 KB
    __shared__ float ssum[H_DIM], ssq[H_DIM];
    int tid = threadIdx.x;
    {
        const float4* wg = (const float4*)W1;
        float4* wl = (float4*)wlds;
        #pragma unroll
        for (int i = 0; i < 8; i++) wl[tid + i * 256] = wg[tid + i * 256];
    }
    if (tid < H_DIM) { ssum[tid] = 0.f; ssq[tid] = 0.f; }
    __syncthreads();

    int rg = tid >> 5, cg = tid & 31;
    int r0 = blockIdx.x * 32 + rg * 4;
    int c0 = cg * 4;
    float acc[4][4];
    {
        float4 bb = *(const float4*)(b1 + c0);
        #pragma unroll
        for (int i = 0; i < 4; i++) {
            acc[i][0] = bb.x; acc[i][1] = bb.y; acc[i][2] = bb.z; acc[i][3] = bb.w;
        }
    }
    #pragma unroll 2
    for (int kc = 0; kc < D_IN; kc += 4) {
        float4 xr[4];
        #pragma unroll
        for (int i = 0; i < 4; i++) {
            int r = r0 + i;
            xr[i] = (r < N_NODES) ? *(const float4*)(x + (size_t)r * D_IN + kc)
                                  : make_float4(0.f, 0.f, 0.f, 0.f);
        }
        #pragma unroll
        for (int kk = 0; kk < 4; kk++) {
            float4 w4 = *(const float4*)&wlds[(kc + kk) * H_DIM + c0];
            #pragma unroll
            for (int i = 0; i < 4; i++) {
                float xv = ((const float*)&xr[i])[kk];
                acc[i][0] = fmaf(xv, w4.x, acc[i][0]);
                acc[i][1] = fmaf(xv, w4.y, acc[i][1]);
                acc[i][2] = fmaf(xv, w4.z, acc[i][2]);
                acc[i][3] = fmaf(xv, w4.w, acc[i][3]);
            }
        }
    }
    float cs[4] = {0.f, 0.f, 0.f, 0.f}, cq[4] = {0.f, 0.f, 0.f, 0.f};
    #pragma unroll
    for (int i = 0; i < 4; i++) {
        int r = r0 + i;
        if (r < N_NODES) {
            *(float4*)(y1 + (size_t)r * H_DIM + c0) =
                make_float4(acc[i][0], acc[i][1], acc[i][2], acc[i][3]);
            #pragma unroll
            for (int j = 0; j < 4; j++) {
                cs[j] += acc[i][j];
                cq[j] += acc[i][j] * acc[i][j];
            }
        }
    }
    #pragma unroll
    for (int j = 0; j < 4; j++) {
        atomicAdd(&ssum[c0 + j], cs[j]);
        atomicAdd(&ssq[c0 + j], cq[j]);
    }
    __syncthreads();
    if (tid < H_DIM) {
        unsafeAtomicAdd(&stats[tid], ssum[tid]);
        unsafeAtomicAdd(&stats[H_DIM + tid], ssq[tid]);
    }
}

// ---------------------------------------------------------------------------
// GEMM2: out = relu(BN(y1)) @ W2 + b2.
// ---------------------------------------------------------------------------
__global__ __launch_bounds__(256) void gemm2_bn(
    const float* __restrict__ y1, const float* __restrict__ W2,
    const float* __restrict__ b2, const float* __restrict__ stats,
    const float* __restrict__ gamma, const float* __restrict__ beta,
    float* __restrict__ out)
{
    __shared__ float wlds[H_DIM * OUT_DIM];   // 32 KB
    __shared__ float sc[H_DIM], sh[H_DIM];
    int tid = threadIdx.x;
    {
        const float4* wg = (const float4*)W2;
        float4* wl = (float4*)wlds;
        #pragma unroll
        for (int i = 0; i < 8; i++) wl[tid + i * 256] = wg[tid + i * 256];
    }
    if (tid < H_DIM) {
        float mean = stats[tid] * (1.f / N_NODES);
        float var  = stats[H_DIM + tid] * (1.f / N_NODES) - mean * mean;
        float rs   = rsqrtf(var + BN_EPS);
        float s    = gamma[tid] * rs;
        sc[tid] = s;
        sh[tid] = beta[tid] - mean * s;
    }
    __syncthreads();

    int rg = tid >> 4, cg = tid & 15;
    int r0 = blockIdx.x * 64 + rg * 4;
    int c0 = cg * 4;
    float acc[4][4];
    {
        float4 bb = *(const float4*)(b2 + c0);
        #pragma unroll
        for (int i = 0; i < 4; i++) {
            acc[i][0] = bb.x; acc[i][1] = bb.y; acc[i][2] = bb.z; acc[i][3] = bb.w;
        }
    }
    #pragma unroll 2
    for (int kc = 0; kc < H_DIM; kc += 4) {
        float4 sc4 = *(const float4*)&sc[kc];
        float4 sh4 = *(const float4*)&sh[kc];
        float4 yr[4];
        #pragma unroll
        for (int i = 0; i < 4; i++) {
            int r = r0 + i;
            if (r < N_NODES) {
                float4 v = *(const float4*)(y1 + (size_t)r * H_DIM + kc);
                v.x = fmaxf(fmaf(v.x, sc4.x, sh4.x), 0.f);
                v.y = fmaxf(fmaf(v.y, sc4.y, sh4.y), 0.f);
                v.z = fmaxf(fmaf(v.z, sc4.z, sh4.z), 0.f);
                v.w = fmaxf(fmaf(v.w, sc4.w, sh4.w), 0.f);
                yr[i] = v;
            } else {
                yr[i] = make_float4(0.f, 0.f, 0.f, 0.f);
            }
        }
        #pragma unroll
        for (int kk = 0; kk < 4; kk++) {
            float4 w4 = *(const float4*)&wlds[(kc + kk) * OUT_DIM + c0];
            #pragma unroll
            for (int i = 0; i < 4; i++) {
                float yv = ((const float*)&yr[i])[kk];
                acc[i][0] = fmaf(yv, w4.x, acc[i][0]);
                acc[i][1] = fmaf(yv, w4.y, acc[i][1]);
                acc[i][2] = fmaf(yv, w4.z, acc[i][2]);
                acc[i][3] = fmaf(yv, w4.w, acc[i][3]);
            }
        }
    }
    #pragma unroll
    for (int i = 0; i < 4; i++) {
        int r = r0 + i;
        if (r < N_NODES) {
            *(float4*)(out + (size_t)r * OUT_DIM + c0) =
                make_float4(acc[i][0], acc[i][1], acc[i][2], acc[i][3]);
        }
    }
}

// ---------------------------------------------------------------------------
// Workspace layout (4-byte elements):
//   counts  int[N]        \ zeroed together (N + 256 elements)
//   stats   float[256]    /
//   bsum    int[512]
//   row_start int[N+1]
//   bcur    int[512]          (bucket cursors, written by scan3b)
//   binned  u64[E]            (12.8 MB, bucket-grouped packed edges)
//   adj     int2[E]           (12.8 MB, dst-sorted)
//   x       float[N*64]
//   y1      float[N*128]
// ---------------------------------------------------------------------------
extern "C" void kernel_launch(void* const* d_in, const int* in_sizes, int n_in,
                              void* d_out, int out_size, void* d_ws, size_t ws_size,
                              hipStream_t stream)
{
    const float* feats   = (const float*)d_in[0];
    const float* edge_h  = (const float*)d_in[1];
    const int*   src     = (const int*)d_in[2];
    const int*   dst     = (const int*)d_in[3];
    const float* W1      = (const float*)d_in[4];
    const float* b1      = (const float*)d_in[5];
    const float* gamma   = (const float*)d_in[6];
    const float* bn_beta = (const float*)d_in[7];
    const float* W2      = (const float*)d_in[8];
    const float* b2      = (const float*)d_in[9];
    const float* scale   = (const float*)d_in[10];
    float* out = (float*)d_out;

    const size_t ND = (size_t)N_NODES * D_IN;
    char* ws = (char*)d_ws;
    int*   counts    = (int*)ws;                          ws += (size_t)N_NODES * 4;
    float* stats     = (float*)ws;                        ws += 256 * 4;
    int*   bsum      = (int*)ws;                          ws += 512 * 4;
    int*   row_start = (int*)ws;                          ws += (size_t)(N_NODES + 1) * 4;
    int*   bcur      = (int*)ws;                          ws += 512 * 4;
    unsigned long long* binned = (unsigned long long*)ws; ws += (size_t)E_EDGES * 8;
    int2*  adj       = (int2*)ws;                         ws += (size_t)E_EDGES * 8;
    float* xbuf      = (float*)ws;                        ws += ND * 4;
    float* y1        = (float*)ws;

    const int NB  = (N_NODES + 255) / 256;               // 391
    const int EB4 = (E_EDGES / 4 + 255) / 256;           // 1563
    const int P1B = (E_EDGES + P1_CHUNK - 1) / P1_CHUNK; // 391

    // zero counts + stats in one memset (contiguous)
    hipMemsetAsync(counts, 0, (size_t)(N_NODES + 256) * 4, stream);

    hist_kernel<<<EB4, 256, 0, stream>>>(dst, counts);
    scan1<<<NB, 256, 0, stream>>>(counts, row_start, bsum);
    scan2<<<1, 512, 0, stream>>>(bsum, NB);
    scan3b<<<NB, 256, 0, stream>>>(counts, bsum, row_start, bcur);
    bin_p1<<<P1B, 256, 0, stream>>>(dst, src, bcur, binned);
    sort_p2<<<NBUCKET, 256, 0, stream>>>(binned, row_start, adj);
    aggregate<<<(N_NODES + 3) / 4, 256, 0, stream>>>(feats, edge_h, adj, row_start, scale, xbuf);
    gemm1_stats<<<(N_NODES + 31) / 32, 256, 0, stream>>>(xbuf, W1, b1, y1, stats);
    gemm2_bn<<<(N_NODES + 63) / 64, 256, 0, stream>>>(y1, W2, b2, stats, gamma, bn_beta, out);
}

// Round 9
// 812.713 us; speedup vs baseline: 1.5806x; 1.0921x over previous
//
#include <hip/hip_runtime.h>
#include <cstdint>

#define N_NODES 100000
#define E_EDGES 1600000
#define D_IN 64
#define H_DIM 128
#define OUT_DIM 64
#define EPS_GEN 1e-7f
#define BN_EPS 1e-5f
#define NORM_EPS 1e-12f

#define NBUCKET 391          // ceil(N/256): bucket b = nodes [b*256, b*256+256)
#define P1_CHUNK 4096        // edges per chunk (last chunk: 2560, mult of 4)

// Clang-native int vector for nontemporal builtins (HIP int4 is a class).
typedef int ivec4 __attribute__((ext_vector_type(4)));

// ---------------------------------------------------------------------------
// Bucket histogram (391 bins): LDS-staged per chunk, then 391 global
// atomics/block. Replaces the per-node hist for the binning stage.
// ---------------------------------------------------------------------------
__global__ __launch_bounds__(256) void bucket_hist(
    const int* __restrict__ dst, int* __restrict__ bc)
{
    __shared__ int c[NBUCKET];
    int tid = threadIdx.x;
    int e0 = blockIdx.x * P1_CHUNK;
    int total = min(P1_CHUNK, E_EDGES - e0);
    for (int b = tid; b < NBUCKET; b += 256) c[b] = 0;
    __syncthreads();
    for (int i4 = tid; i4 * 4 < total; i4 += 256) {
        ivec4 d = __builtin_nontemporal_load((const ivec4*)(dst + e0) + i4);
        atomicAdd(&c[d.x >> 8], 1);
        atomicAdd(&c[d.y >> 8], 1);
        atomicAdd(&c[d.z >> 8], 1);
        atomicAdd(&c[d.w >> 8], 1);
    }
    __syncthreads();
    for (int b = tid; b < NBUCKET; b += 256)
        if (c[b]) atomicAdd(&bc[b], c[b]);
}

// ---------------------------------------------------------------------------
// Exclusive scan of the 391 bucket counts (single block) -> stable bases
// bbase[0..NBUCKET] and working cursors bcur[].
// ---------------------------------------------------------------------------
__global__ __launch_bounds__(512) void bucket_scan(
    const int* __restrict__ bc, int* __restrict__ bbase, int* __restrict__ bcur)
{
    __shared__ int s[512];
    int t = threadIdx.x;
    int v = (t < NBUCKET) ? bc[t] : 0;
    s[t] = v;
    __syncthreads();
    #pragma unroll
    for (int off = 1; off < 512; off <<= 1) {
        int u = (t >= off) ? s[t - off] : 0;
        __syncthreads();
        s[t] += u;
        __syncthreads();
    }
    if (t < NBUCKET) {
        int ex = s[t] - v;      // exclusive
        bbase[t] = ex;
        bcur[t]  = ex;
    }
    if (t == 0) bbase[NBUCKET] = E_EDGES;
}

// ---------------------------------------------------------------------------
// Bin P1: partition edges by bucket = dst>>8 with LDS staging; flush is
// FULLY PARALLEL: thread handles entry i via 9-step binary search over
// base_l (consecutive i -> same path -> LDS broadcast; consecutive dests ->
// coalesced global stores). Pack: dst_local(8)|src(17)|eid(21) in u64.
// ---------------------------------------------------------------------------
__global__ __launch_bounds__(256) void bin_p1(
    const int* __restrict__ dst, const int* __restrict__ src,
    int* __restrict__ bcur, unsigned long long* __restrict__ binned)
{
    __shared__ unsigned long long buf[P1_CHUNK];   // 32 KB
    __shared__ int cnt[NBUCKET];
    __shared__ int base_l[NBUCKET];
    __shared__ int pos[NBUCKET];
    __shared__ int gb[NBUCKET];
    __shared__ int s[256];
    int tid = threadIdx.x;
    int e0 = blockIdx.x * P1_CHUNK;
    int total = min(P1_CHUNK, E_EDGES - e0);   // always a multiple of 4

    for (int b = tid; b < NBUCKET; b += 256) cnt[b] = 0;
    __syncthreads();
    // pass 1: count buckets (vectorized)
    for (int i4 = tid; i4 * 4 < total; i4 += 256) {
        ivec4 d = ((const ivec4*)(dst + e0))[i4];
        atomicAdd(&cnt[d.x >> 8], 1);
        atomicAdd(&cnt[d.y >> 8], 1);
        atomicAdd(&cnt[d.z >> 8], 1);
        atomicAdd(&cnt[d.w >> 8], 1);
    }
    __syncthreads();
    // exclusive scan of cnt (2 entries/thread, Hillis-Steele)
    int a0 = (2 * tid     < NBUCKET) ? cnt[2 * tid]     : 0;
    int a1 = (2 * tid + 1 < NBUCKET) ? cnt[2 * tid + 1] : 0;
    s[tid] = a0 + a1;
    __syncthreads();
    #pragma unroll
    for (int off = 1; off < 256; off <<= 1) {
        int u = (tid >= off) ? s[tid - off] : 0;
        __syncthreads();
        s[tid] += u;
        __syncthreads();
    }
    int pb = s[tid] - a0 - a1;
    if (2 * tid < NBUCKET)     { base_l[2 * tid] = pb;          pos[2 * tid] = pb; }
    if (2 * tid + 1 < NBUCKET) { base_l[2 * tid + 1] = pb + a0; pos[2 * tid + 1] = pb + a0; }
    __syncthreads();
    // claim global space per bucket (before fill; flush needs gb)
    for (int b = tid; b < NBUCKET; b += 256) {
        int c = cnt[b];
        gb[b] = c ? atomicAdd(&bcur[b], c) : 0;
    }
    // pass 2: fill buf grouped by bucket (vectorized reads)
    __syncthreads();
    for (int i4 = tid; i4 * 4 < total; i4 += 256) {
        ivec4 d  = ((const ivec4*)(dst + e0))[i4];
        ivec4 sr = ((const ivec4*)(src + e0))[i4];
        int e = e0 + 4 * i4;
        #pragma unroll
        for (int k = 0; k < 4; k++) {
            int dd = (k == 0) ? d.x : (k == 1) ? d.y : (k == 2) ? d.z : d.w;
            int ss = (k == 0) ? sr.x : (k == 1) ? sr.y : (k == 2) ? sr.z : sr.w;
            int b = dd >> 8;
            int p = atomicAdd(&pos[b], 1);
            buf[p] = ((unsigned long long)(dd & 255) << 38)
                   | ((unsigned long long)(unsigned)ss << 21)
                   | (unsigned long long)(e + k);
        }
    }
    __syncthreads();
    // flush: parallel, coalesced
    for (int i = tid; i < total; i += 256) {
        int lo = 0, hi = NBUCKET - 1;
        while (lo < hi) {
            int mid = (lo + hi + 1) >> 1;
            if (base_l[mid] <= i) lo = mid; else hi = mid - 1;
        }
        binned[(size_t)gb[lo] + (i - base_l[lo])] = buf[i];
    }
}

// ---------------------------------------------------------------------------
// Sort P2 (+ fused per-node row_start): one block per bucket.
// Pass A counts nodes; in-block scan -> row_start slice; pass B places adj
// inside the bucket's 32KB window (L2-coalesced writes).
// ---------------------------------------------------------------------------
__global__ __launch_bounds__(256) void sort_p2(
    const unsigned long long* __restrict__ binned,
    const int* __restrict__ bbase, int* __restrict__ row_start,
    int2* __restrict__ adj)
{
    __shared__ int lcnt[256], ncur[256];
    __shared__ int s[256];
    int b = blockIdx.x, tid = threadIdx.x;
    int node_base = b << 8;
    int base  = bbase[b];
    int count = bbase[b + 1] - base;
    lcnt[tid] = 0;
    __syncthreads();
    // pass A: per-node counts
    for (int i = tid; i < count; i += 256) {
        int dl = (int)(binned[(size_t)base + i] >> 38);
        atomicAdd(&lcnt[dl], 1);
    }
    __syncthreads();
    // exclusive scan of 256 node counts
    int v = lcnt[tid];
    s[tid] = v;
    __syncthreads();
    #pragma unroll
    for (int off = 1; off < 256; off <<= 1) {
        int u = (tid >= off) ? s[tid - off] : 0;
        __syncthreads();
        s[tid] += u;
        __syncthreads();
    }
    int excl = s[tid] - v;
    ncur[tid] = excl;
    int node = node_base + tid;
    if (node < N_NODES) row_start[node] = base + excl;
    if (b == NBUCKET - 1 && tid == 0) row_start[N_NODES] = E_EDGES;
    __syncthreads();
    // pass B: place entries (binned bucket slice is L2-hot from pass A)
    for (int i = tid; i < count; i += 256) {
        unsigned long long w = binned[(size_t)base + i];
        int dl  = (int)(w >> 38);
        int p   = atomicAdd(&ncur[dl], 1);
        int eid = (int)(w & 0x1FFFFFull);
        int sr  = (int)((w >> 21) & 0x1FFFFull);
        adj[(size_t)base + p] = make_int2(eid, sr);
    }
}

// ---------------------------------------------------------------------------
// Fused aggregation + MessageNorm (proven round-3 version, unchanged).
// One wave per node, lane = channel; adj coalesced + shfl-broadcast;
// masked unroll x8 (16 row loads in flight); edge_h NT.
//   den = sum exp(m), hn = sum m*exp(m)  (max-shift cancels; m ~ [1e-7,10])
// ---------------------------------------------------------------------------
__global__ __launch_bounds__(256) void aggregate(
    const float* __restrict__ feats, const float* __restrict__ edge_h,
    const int2* __restrict__ adj, const int* __restrict__ row_start,
    const float* __restrict__ scale, float* __restrict__ x)
{
    int node = blockIdx.x * 4 + (threadIdx.x >> 6);
    int lane = threadIdx.x & 63;
    if (node >= N_NODES) return;
    int rs = row_start[node], re = row_start[node + 1];
    float den = 0.f, hn = 0.f;

    for (int base = rs; base < re; base += 64) {
        int rem = min(64, re - base);
        int2 ad = make_int2(0, 0);
        if (base + lane < re) {
            unsigned long long v = __builtin_nontemporal_load(
                (const unsigned long long*)&adj[base + lane]);
            ad.x = (int)(unsigned)v;
            ad.y = (int)(unsigned)(v >> 32);
        }
        for (int j = 0; j < rem; j += 8) {
            #pragma unroll
            for (int u = 0; u < 8; u++) {
                int jj = j + u;
                int eid = __shfl(ad.x, jj);
                int sid = __shfl(ad.y, jj);
                float fv = feats[(size_t)sid * D_IN + lane];
                float ev = __builtin_nontemporal_load(
                               &edge_h[(size_t)eid * D_IN + lane]);
                float m = fmaxf(fv + ev, 0.f) + EPS_GEN;
                float ex = __expf(m);
                bool ok = jj < rem;
                den += ok ? ex : 0.f;
                hn  += ok ? m * ex : 0.f;
            }
        }
    }

    float h = den > 0.f ? hn / den : 0.f;
    float f = feats[(size_t)node * D_IN + lane];
    float s1 = h * h, s2 = f * f;
    #pragma unroll
    for (int off = 32; off > 0; off >>= 1) {
        s1 += __shfl_xor(s1, off, 64);
        s2 += __shfl_xor(s2, off, 64);
    }
    float xv = f + (h / fmaxf(sqrtf(s1), NORM_EPS)) * sqrtf(s2) * scale[0];
    x[(size_t)node * D_IN + lane] = xv;
}

// ---------------------------------------------------------------------------
// GEMM1: y1 = x[N,64] @ W1[64,128] + b1, fused BN batch-stat partials.
// ---------------------------------------------------------------------------
__global__ __launch_bounds__(256) void gemm1_stats(
    const float* __restrict__ x, const float* __restrict__ W1,
    const float* __restrict__ b1, float* __restrict__ y1,
    float* __restrict__ stats)
{
    __shared__ float wlds[D_IN * H_DIM];   // 32 KB
    __shared__ float ssum[H_DIM], ssq[H_DIM];
    int tid = threadIdx.x;
    {
        const float4* wg = (const float4*)W1;
        float4* wl = (float4*)wlds;
        #pragma unroll
        for (int i = 0; i < 8; i++) wl[tid + i * 256] = wg[tid + i * 256];
    }
    if (tid < H_DIM) { ssum[tid] = 0.f; ssq[tid] = 0.f; }
    __syncthreads();

    int rg = tid >> 5, cg = tid & 31;
    int r0 = blockIdx.x * 32 + rg * 4;
    int c0 = cg * 4;
    float acc[4][4];
    {
        float4 bb = *(const float4*)(b1 + c0);
        #pragma unroll
        for (int i = 0; i < 4; i++) {
            acc[i][0] = bb.x; acc[i][1] = bb.y; acc[i][2] = bb.z; acc[i][3] = bb.w;
        }
    }
    #pragma unroll 2
    for (int kc = 0; kc < D_IN; kc += 4) {
        float4 xr[4];
        #pragma unroll
        for (int i = 0; i < 4; i++) {
            int r = r0 + i;
            xr[i] = (r < N_NODES) ? *(const float4*)(x + (size_t)r * D_IN + kc)
                                  : make_float4(0.f, 0.f, 0.f, 0.f);
        }
        #pragma unroll
        for (int kk = 0; kk < 4; kk++) {
            float4 w4 = *(const float4*)&wlds[(kc + kk) * H_DIM + c0];
            #pragma unroll
            for (int i = 0; i < 4; i++) {
                float xv = ((const float*)&xr[i])[kk];
                acc[i][0] = fmaf(xv, w4.x, acc[i][0]);
                acc[i][1] = fmaf(xv, w4.y, acc[i][1]);
                acc[i][2] = fmaf(xv, w4.z, acc[i][2]);
                acc[i][3] = fmaf(xv, w4.w, acc[i][3]);
            }
        }
    }
    float cs[4] = {0.f, 0.f, 0.f, 0.f}, cq[4] = {0.f, 0.f, 0.f, 0.f};
    #pragma unroll
    for (int i = 0; i < 4; i++) {
        int r = r0 + i;
        if (r < N_NODES) {
            *(float4*)(y1 + (size_t)r * H_DIM + c0) =
                make_float4(acc[i][0], acc[i][1], acc[i][2], acc[i][3]);
            #pragma unroll
            for (int j = 0; j < 4; j++) {
                cs[j] += acc[i][j];
                cq[j] += acc[i][j] * acc[i][j];
            }
        }
    }
    #pragma unroll
    for (int j = 0; j < 4; j++) {
        atomicAdd(&ssum[c0 + j], cs[j]);
        atomicAdd(&ssq[c0 + j], cq[j]);
    }
    __syncthreads();
    if (tid < H_DIM) {
        unsafeAtomicAdd(&stats[tid], ssum[tid]);
        unsafeAtomicAdd(&stats[H_DIM + tid], ssq[tid]);
    }
}

// ---------------------------------------------------------------------------
// GEMM2: out = relu(BN(y1)) @ W2 + b2.
// ---------------------------------------------------------------------------
__global__ __launch_bounds__(256) void gemm2_bn(
    const float* __restrict__ y1, const float* __restrict__ W2,
    const float* __restrict__ b2, const float* __restrict__ stats,
    const float* __restrict__ gamma, const float* __restrict__ beta,
    float* __restrict__ out)
{
    __shared__ float wlds[H_DIM * OUT_DIM];   // 32 KB
    __shared__ float sc[H_DIM], sh[H_DIM];
    int tid = threadIdx.x;
    {
        const float4* wg = (const float4*)W2;
        float4* wl = (float4*)wlds;
        #pragma unroll
        for (int i = 0; i < 8; i++) wl[tid + i * 256] = wg[tid + i * 256];
    }
    if (tid < H_DIM) {
        float mean = stats[tid] * (1.f / N_NODES);
        float var  = stats[H_DIM + tid] * (1.f / N_NODES) - mean * mean;
        float rs   = rsqrtf(var + BN_EPS);
        float s    = gamma[tid] * rs;
        sc[tid] = s;
        sh[tid] = beta[tid] - mean * s;
    }
    __syncthreads();

    int rg = tid >> 4, cg = tid & 15;
    int r0 = blockIdx.x * 64 + rg * 4;
    int c0 = cg * 4;
    float acc[4][4];
    {
        float4 bb = *(const float4*)(b2 + c0);
        #pragma unroll
        for (int i = 0; i < 4; i++) {
            acc[i][0] = bb.x; acc[i][1] = bb.y; acc[i][2] = bb.z; acc[i][3] = bb.w;
        }
    }
    #pragma unroll 2
    for (int kc = 0; kc < H_DIM; kc += 4) {
        float4 sc4 = *(const float4*)&sc[kc];
        float4 sh4 = *(const float4*)&sh[kc];
        float4 yr[4];
        #pragma unroll
        for (int i = 0; i < 4; i++) {
            int r = r0 + i;
            if (r < N_NODES) {
                float4 v = *(const float4*)(y1 + (size_t)r * H_DIM + kc);
                v.x = fmaxf(fmaf(v.x, sc4.x, sh4.x), 0.f);
                v.y = fmaxf(fmaf(v.y, sc4.y, sh4.y), 0.f);
                v.z = fmaxf(fmaf(v.z, sc4.z, sh4.z), 0.f);
                v.w = fmaxf(fmaf(v.w, sc4.w, sh4.w), 0.f);
                yr[i] = v;
            } else {
                yr[i] = make_float4(0.f, 0.f, 0.f, 0.f);
            }
        }
        #pragma unroll
        for (int kk = 0; kk < 4; kk++) {
            float4 w4 = *(const float4*)&wlds[(kc + kk) * OUT_DIM + c0];
            #pragma unroll
            for (int i = 0; i < 4; i++) {
                float yv = ((const float*)&yr[i])[kk];
                acc[i][0] = fmaf(yv, w4.x, acc[i][0]);
                acc[i][1] = fmaf(yv, w4.y, acc[i][1]);
                acc[i][2] = fmaf(yv, w4.z, acc[i][2]);
                acc[i][3] = fmaf(yv, w4.w, acc[i][3]);
            }
        }
    }
    #pragma unroll
    for (int i = 0; i < 4; i++) {
        int r = r0 + i;
        if (r < N_NODES) {
            *(float4*)(out + (size_t)r * OUT_DIM + c0) =
                make_float4(acc[i][0], acc[i][1], acc[i][2], acc[i][3]);
        }
    }
}

// ---------------------------------------------------------------------------
// Workspace layout (4-byte elements):
//   bc      int[512]      \ zeroed together (512 + 256 elements, 3 KB)
//   stats   float[256]    /
//   bbase   int[512]          (stable bucket bases, [NBUCKET] = E)
//   bcur    int[512]          (working cursors)
//   row_start int[N+1]        (written by sort_p2)
//   binned  u64[E]            (12.8 MB, bucket-grouped packed edges)
//   adj     int2[E]           (12.8 MB, dst-sorted)
//   x       float[N*64]
//   y1      float[N*128]
// ---------------------------------------------------------------------------
extern "C" void kernel_launch(void* const* d_in, const int* in_sizes, int n_in,
                              void* d_out, int out_size, void* d_ws, size_t ws_size,
                              hipStream_t stream)
{
    const float* feats   = (const float*)d_in[0];
    const float* edge_h  = (const float*)d_in[1];
    const int*   src     = (const int*)d_in[2];
    const int*   dst     = (const int*)d_in[3];
    const float* W1      = (const float*)d_in[4];
    const float* b1      = (const float*)d_in[5];
    const float* gamma   = (const float*)d_in[6];
    const float* bn_beta = (const float*)d_in[7];
    const float* W2      = (const float*)d_in[8];
    const float* b2      = (const float*)d_in[9];
    const float* scale   = (const float*)d_in[10];
    float* out = (float*)d_out;

    const size_t ND = (size_t)N_NODES * D_IN;
    char* ws = (char*)d_ws;
    int*   bc        = (int*)ws;                          ws += 512 * 4;
    float* stats     = (float*)ws;                        ws += 256 * 4;
    int*   bbase     = (int*)ws;                          ws += 512 * 4;
    int*   bcur      = (int*)ws;                          ws += 512 * 4;
    int*   row_start = (int*)ws;                          ws += (size_t)(N_NODES + 1) * 4;
    unsigned long long* binned = (unsigned long long*)ws; ws += (size_t)E_EDGES * 8;
    int2*  adj       = (int2*)ws;                         ws += (size_t)E_EDGES * 8;
    float* xbuf      = (float*)ws;                        ws += ND * 4;
    float* y1        = (float*)ws;

    const int P1B = (E_EDGES + P1_CHUNK - 1) / P1_CHUNK; // 391

    // zero bc + stats in one tiny memset (contiguous, 3 KB)
    hipMemsetAsync(bc, 0, (512 + 256) * 4, stream);

    bucket_hist<<<P1B, 256, 0, stream>>>(dst, bc);
    bucket_scan<<<1, 512, 0, stream>>>(bc, bbase, bcur);
    bin_p1<<<P1B, 256, 0, stream>>>(dst, src, bcur, binned);
    sort_p2<<<NBUCKET, 256, 0, stream>>>(binned, bbase, row_start, adj);
    aggregate<<<(N_NODES + 3) / 4, 256, 0, stream>>>(feats, edge_h, adj, row_start, scale, xbuf);
    gemm1_stats<<<(N_NODES + 31) / 32, 256, 0, stream>>>(xbuf, W1, b1, y1, stats);
    gemm2_bn<<<(N_NODES + 63) / 64, 256, 0, stream>>>(y1, W2, b2, stats, gamma, bn_beta, out);
}